// Round 11
// baseline (309.899 us; speedup 1.0000x reference)
//
#include <hip/hip_runtime.h>

#define NN 100000
#define NE 1600000
#define NBUCK 1563     // ceil(NN/64)
#define NBH 256        // histogram/placement chunks
#define CHUNK 6250     // NE/NBH
#define NSEG 8         // k_scanB segments per bucket
#define SEGC (NBH/NSEG) // 32 chunks per segment
#define NBXB 12500     // NN*32/256 blocks for x->bf16
#define NBG 1563       // row tiles for GEMMs
#define NBGG 1024      // k_g1/k_g2 grid (1-2 tiles/block, 4 blocks/CU resident)

// ws layout (bytes):
//   xb:    0           (25,600,000)  bf16 x             [live: k_pre..k_agg1]
//   H:     0           (25,600,000)  relu(agg@W1+b1) bf16 row-major [k_g1..k_g2] (overlaps dead xb)
//   P:     25,600,000  (25,600,000)  agg_x bf16 256B/node [k_agg1..k_g1]
//   T2:    25,600,000  (12,800,000)  t2 bf16 dense 128B/node [k_g2..k_agg2] (overlaps dead P)
//     ghist: 25,600,000 (1,600,512)  dead after k_scanB  (overlaps P, pre-agg1)
//     boffT: 27,200,512 (1,600,512)  dead after k_place
//     tot:   28,801,024 (6,252)      dead after k_binC
//     bbase: 28,807,276 (6,252)      written by k_place blk0; dead after k_binC
//   row_start: 51,200,000 ((NN+1)*4)
//   dinv:  51,600,004  (400,000)
//   csr:   52,000,004  (6,400,000)
//   ebuf:  58,400,004  (6,400,000)   dead after k_binC
// total 64.8 MB. No memsets needed.

typedef short bf16x8 __attribute__((ext_vector_type(8)));
typedef float f32x4  __attribute__((ext_vector_type(4)));
typedef float f32x2  __attribute__((ext_vector_type(2)));

__device__ __forceinline__ float b2f(unsigned short u) {
    return __uint_as_float(((unsigned int)u) << 16);
}
__device__ __forceinline__ unsigned short f2b(float f) {
    unsigned int x = __float_as_uint(f);
    x += 0x7FFFu + ((x >> 16) & 1u);   // RNE
    return (unsigned short)(x >> 16);
}

// ---- fused: x->bf16 (blocks [0,NBXB)) + bucket histogram (blocks [NBXB,NBXB+NBH)) ----
__global__ __launch_bounds__(256) void k_pre(const float* __restrict__ x,
                                             unsigned short* __restrict__ xb,
                                             const int* __restrict__ dst,
                                             int* __restrict__ ghist) {
    int b = blockIdx.x;
    if (b < NBXB) {
        int id = b * 256 + threadIdx.x;
        float4 v = ((const float4*)x)[id];
        ushort4 o;
        o.x = f2b(v.x); o.y = f2b(v.y); o.z = f2b(v.z); o.w = f2b(v.w);
        ((ushort4*)xb)[id] = o;
        return;
    }
    __shared__ int h[NBUCK];
    int tid = threadIdx.x;
    int i = b - NBXB;
    for (int k = tid; k < NBUCK; k += 256) h[k] = 0;
    __syncthreads();
    int e0 = i * CHUNK;
    for (int e = e0 + tid; e < e0 + CHUNK; e += 256) {
        unsigned d = (unsigned)dst[e];
        if (d < NN) atomicAdd(&h[d >> 6], 1);
    }
    __syncthreads();
    for (int k = tid; k < NBUCK; k += 256) ghist[i * NBUCK + k] = h[k];
}

// ---- per-bucket scan over chunks, 8-way segmented: boffT[i][k], tot[k] ----
__global__ __launch_bounds__(256) void k_scanB(const int* __restrict__ ghist,
                                               int* __restrict__ boffT,
                                               int* __restrict__ tot) {
    __shared__ int part[NSEG][32];
    int kk = threadIdx.x & 31, seg = threadIdx.x >> 5;
    int k = blockIdx.x * 32 + kk;
    bool ok = (k < NBUCK);
    int i0 = seg * SEGC;
    int S = 0;
    if (ok) {
#pragma unroll 8
        for (int i = i0; i < i0 + SEGC; ++i) S += ghist[i * NBUCK + k];
    }
    part[seg][kk] = S;
    __syncthreads();
    int pre = 0;
#pragma unroll
    for (int s2 = 0; s2 < NSEG; ++s2) pre += (s2 < seg) ? part[s2][kk] : 0;
    if (ok) {
        int run = pre;
#pragma unroll 8
        for (int i = i0; i < i0 + SEGC; ++i) {
            int c = ghist[i * NBUCK + k];
            boffT[i * NBUCK + k] = run;      // coalesced in k
            run += c;
        }
        if (seg == NSEG - 1) tot[k] = run;
    }
}

// ---- placement: computes bbase locally (scanT folded in), XCD-swizzled chunks ----
__global__ __launch_bounds__(256) void k_place(const int* __restrict__ src,
                                               const int* __restrict__ dst,
                                               const int* __restrict__ tot,
                                               const int* __restrict__ boffT,
                                               int* __restrict__ ebuf,
                                               int* __restrict__ bbase_out) {
    __shared__ int cur[NBUCK];
    __shared__ int s[256];
    const int tid = threadIdx.x, bid = blockIdx.x;
    const int i = ((bid & 7) * (NBH / 8)) + (bid >> 3);   // consecutive chunks same XCD
    int k0 = tid * 7;
    int v[7]; int S = 0;
#pragma unroll
    for (int q = 0; q < 7; ++q) {
        int k = k0 + q;
        v[q] = (k < NBUCK) ? tot[k] : 0;
        S += v[q];
    }
    s[tid] = S;
    __syncthreads();
    for (int off = 1; off < 256; off <<= 1) {
        int t = (tid >= off) ? s[tid - off] : 0;
        __syncthreads();
        s[tid] += t;
        __syncthreads();
    }
    int run = s[tid] - S;   // exclusive
#pragma unroll
    for (int q = 0; q < 7; ++q) {
        int k = k0 + q;
        if (k < NBUCK) {
            cur[k] = run + boffT[i * NBUCK + k];
            if (bid == 0) bbase_out[k] = run;    // publish for k_binC
            run += v[q];
        }
    }
    __syncthreads();
    int e0 = i * CHUNK;
    for (int e = e0 + tid; e < e0 + CHUNK; e += 256) {
        unsigned d = (unsigned)dst[e];
        if (d >= NN) continue;
        unsigned sv = (unsigned)src[e];
        if (sv >= NN) sv = 0;
        int pos = atomicAdd(&cur[d >> 6], 1);
        ebuf[pos] = (int)(sv | ((d & 63u) << 17));
    }
}

// ---- per-bucket: count per node, write row_start/dinv, place src-only csr ----
__global__ __launch_bounds__(256) void k_binC(const int* __restrict__ bbase,
                                              const int* __restrict__ tot,
                                              const int* __restrict__ ebuf,
                                              int* __restrict__ row_start,
                                              float* __restrict__ dinv,
                                              int* __restrict__ csr) {
    __shared__ int cnt[64], excl[64], cur[64];
    int b = blockIdx.x, tid = threadIdx.x;
    int n0 = b * 64;
    int base = bbase[b], end = base + tot[b];
    if (tid < 64) cnt[tid] = 0;
    __syncthreads();
    for (int i = base + tid; i < end; i += 256)
        atomicAdd(&cnt[((unsigned)ebuf[i]) >> 17], 1);
    __syncthreads();
    if (tid == 0) {
        int run = 0;
        for (int t = 0; t < 64; ++t) { excl[t] = run; run += cnt[t]; }
    }
    __syncthreads();
    if (tid < 64) {
        int node = n0 + tid;
        if (node < NN) {
            row_start[node] = base + excl[tid];
            dinv[node] = rsqrtf((float)cnt[tid] + 1.0f);
        }
        cur[tid] = base + excl[tid];
    }
    if (b == NBUCK - 1 && tid == 0) row_start[NN] = end;
    __syncthreads();
    for (int i = base + tid; i < end; i += 256) {
        unsigned rec = (unsigned)ebuf[i];
        int pos = atomicAdd(&cur[rec >> 17], 1);
        csr[pos] = (int)(rec & 0x1FFFFu);
    }
}

// ---- layer-1 aggregate: 4 neighbor rows PER GATHER INSTRUCTION (at service roofline) ----
__global__ __launch_bounds__(256) void k_agg1(const unsigned short* __restrict__ xb,
                                              const float* __restrict__ dinv,
                                              const int* __restrict__ row_start,
                                              const int* __restrict__ csr,
                                              char* __restrict__ P) {
    int node = blockIdx.x * 4 + (threadIdx.x >> 6);   // grid = NN/4 exactly
    int lane = threadIdx.x & 63;
    int sub  = lane >> 4;          // edge slot within group of 4
    int dimb = lane & 15;          // 16B chunk within 256B row
    const uint4* X4 = (const uint4*)xb;   // 16 uint4 per 256B row
    float dv = dinv[node];
    float sn4 = dv * dv * 0.25f;   // exact /4: 4 identical partials sum back to x*sn
    uint4 sv = X4[(size_t)node * 16 + dimb];
    f32x2 a0, a1, a2, a3;
    a0.x = __uint_as_float(sv.x << 16) * sn4;  a0.y = __uint_as_float(sv.x & 0xFFFF0000u) * sn4;
    a1.x = __uint_as_float(sv.y << 16) * sn4;  a1.y = __uint_as_float(sv.y & 0xFFFF0000u) * sn4;
    a2.x = __uint_as_float(sv.z << 16) * sn4;  a2.y = __uint_as_float(sv.z & 0xFFFF0000u) * sn4;
    a3.x = __uint_as_float(sv.w << 16) * sn4;  a3.y = __uint_as_float(sv.w & 0xFFFF0000u) * sn4;
    int base = row_start[node], end = row_start[node + 1];
    for (int c0 = base; c0 < end; c0 += 64) {
        int idx = c0 + lane;
        int cl = min(idx, end - 1);
        int s = csr[cl];
        float wv = (idx < end) ? dinv[s] * dv : 0.f;   // clamp lanes neutralized
        int ng = min(64, end - c0);
        for (int g = 0; g * 4 < ng; ++g) {
            int   sq = __shfl(s,  g * 4 + sub);
            float wq = __shfl(wv, g * 4 + sub);
            uint4 v = X4[(size_t)sq * 16 + dimb];      // 4 rows per instruction
            f32x2 wv2; wv2.x = wq; wv2.y = wq;
            f32x2 xv;
            xv.x = __uint_as_float(v.x << 16); xv.y = __uint_as_float(v.x & 0xFFFF0000u);
            a0 = __builtin_elementwise_fma(xv, wv2, a0);
            xv.x = __uint_as_float(v.y << 16); xv.y = __uint_as_float(v.y & 0xFFFF0000u);
            a1 = __builtin_elementwise_fma(xv, wv2, a1);
            xv.x = __uint_as_float(v.z << 16); xv.y = __uint_as_float(v.z & 0xFFFF0000u);
            a2 = __builtin_elementwise_fma(xv, wv2, a2);
            xv.x = __uint_as_float(v.w << 16); xv.y = __uint_as_float(v.w & 0xFFFF0000u);
            a3 = __builtin_elementwise_fma(xv, wv2, a3);
        }
    }
    // butterfly reduce the 4 edge-slot partials (lanes xor 16, 32)
#pragma unroll
    for (int mgap = 16; mgap < 64; mgap <<= 1) {
        a0.x += __shfl_xor(a0.x, mgap); a0.y += __shfl_xor(a0.y, mgap);
        a1.x += __shfl_xor(a1.x, mgap); a1.y += __shfl_xor(a1.y, mgap);
        a2.x += __shfl_xor(a2.x, mgap); a2.y += __shfl_xor(a2.y, mgap);
        a3.x += __shfl_xor(a3.x, mgap); a3.y += __shfl_xor(a3.y, mgap);
    }
    if (lane < 16) {
        uint4 o;
        o.x = (unsigned)f2b(a0.x) | ((unsigned)f2b(a0.y) << 16);
        o.y = (unsigned)f2b(a1.x) | ((unsigned)f2b(a1.y) << 16);
        o.z = (unsigned)f2b(a2.x) | ((unsigned)f2b(a2.y) << 16);
        o.w = (unsigned)f2b(a3.x) | ((unsigned)f2b(a3.y) << 16);
        ((uint4*)(P + (size_t)node * 256))[lane] = o;
    }
}

// ---- GEMM1: H = bf16(relu(agg@W1 + b1)), row-major 128 bf16/node.
//      LDS = Wl1 only (32KB) -> 4+ blocks/CU, no per-tile barriers.
__global__ __launch_bounds__(256) void k_g1(const char* __restrict__ P,
                                            const float* __restrict__ W1,
                                            const float* __restrict__ b1,
                                            unsigned short* __restrict__ H) {
    __shared__ short Wl1[16384];                    // [ct8][ks4][lane64][j8]
    const int tid = threadIdx.x;
    const int w = tid >> 6, lane = tid & 63;
    const int quad = lane >> 4, l15 = lane & 15;

    for (int i = tid; i < 16384; i += 256) {
        int j = i & 7, l = (i >> 3) & 63, ks = (i >> 9) & 3, ct = i >> 11;
        int k = ks * 32 + ((l >> 4) << 3) + j;
        int c = ct * 16 + (l & 15);
        Wl1[i] = (short)f2b(W1[k * 128 + c]);
    }
    float bias1[8];
#pragma unroll
    for (int ct = 0; ct < 8; ++ct) bias1[ct] = b1[ct * 16 + l15];
    __syncthreads();   // only barrier

    for (int t = blockIdx.x; t < NBG; t += NBGG) {
        const int r0 = t * 64;
        const int m = r0 + w * 16 + l15;
        const bool mok = (m < NN);
        bf16x8 a[4];
#pragma unroll
        for (int ks = 0; ks < 4; ++ks) {
            if (mok) a[ks] = *(const bf16x8*)(P + (size_t)m * 256 + (ks * 32 + quad * 8) * 2);
            else     a[ks] = bf16x8{0,0,0,0,0,0,0,0};
        }
#pragma unroll
        for (int ct = 0; ct < 8; ++ct) {
            f32x4 c = {0.f, 0.f, 0.f, 0.f};
#pragma unroll
            for (int ks = 0; ks < 4; ++ks) {
                bf16x8 b = *(const bf16x8*)&Wl1[((ct * 4 + ks) * 64 + lane) * 8];
                c = __builtin_amdgcn_mfma_f32_16x16x32_bf16(a[ks], b, c, 0, 0, 0);
            }
#pragma unroll
            for (int r = 0; r < 4; ++r) {
                int row = r0 + w * 16 + quad * 4 + r;
                if (row < NN)
                    H[(size_t)row * 128 + ct * 16 + l15] =
                        (unsigned short)f2b(fmaxf(c[r] + bias1[ct], 0.f));
            }
        }
    }
}

// ---- GEMM2: T2 = bf16(H @ W2), dense 64 bf16 (128B)/node.
//      H row-major IS the MFMA A-fragment layout -> direct b128 loads, no transpose.
//      LDS = Wl2 only (16KB).
__global__ __launch_bounds__(256) void k_g2(const unsigned short* __restrict__ H,
                                            const float* __restrict__ W2,
                                            unsigned short* __restrict__ T2) {
    __shared__ short Wl2[8192];                     // [ct4][ks4][lane64][j8]
    const int tid = threadIdx.x;
    const int w = tid >> 6, lane = tid & 63;
    const int quad = lane >> 4, l15 = lane & 15;

    for (int i = tid; i < 8192; i += 256) {
        int j = i & 7, l = (i >> 3) & 63, ks = (i >> 9) & 3, ct = i >> 11;
        int k = ks * 32 + ((l >> 4) << 3) + j;
        int c = ct * 16 + (l & 15);
        Wl2[i] = (short)f2b(W2[k * 64 + c]);
    }
    __syncthreads();   // only barrier

    for (int t = blockIdx.x; t < NBG; t += NBGG) {
        const int r0 = t * 64;
        const int m = r0 + w * 16 + l15;
        const bool mok = (m < NN);
        bf16x8 a2[4];
#pragma unroll
        for (int ks = 0; ks < 4; ++ks) {
            if (mok) a2[ks] = *(const bf16x8*)&H[(size_t)m * 128 + ks * 32 + quad * 8];
            else     a2[ks] = bf16x8{0,0,0,0,0,0,0,0};
        }
#pragma unroll
        for (int ct = 0; ct < 4; ++ct) {
            f32x4 c = {0.f, 0.f, 0.f, 0.f};
#pragma unroll
            for (int ks = 0; ks < 4; ++ks) {
                bf16x8 b = *(const bf16x8*)&Wl2[((ct * 4 + ks) * 64 + lane) * 8];
                c = __builtin_amdgcn_mfma_f32_16x16x32_bf16(a2[ks], b, c, 0, 0, 0);
            }
#pragma unroll
            for (int r = 0; r < 4; ++r) {
                int node = r0 + w * 16 + quad * 4 + r;
                if (node < NN)
                    T2[(size_t)node * 64 + ct * 16 + l15] = (unsigned short)f2b(c[r]);
            }
        }
    }
}

// ---- layer-2 aggregate + epilogue: 8 neighbor rows PER GATHER INSTRUCTION,
//      reads dense T2 (128B rows). ----
__global__ __launch_bounds__(256) void k_agg2(const float* __restrict__ dinv,
                                              const int* __restrict__ row_start,
                                              const int* __restrict__ csr,
                                              const unsigned short* __restrict__ T2,
                                              const float* __restrict__ b2,
                                              float* __restrict__ outp) {
    int node = blockIdx.x * 4 + (threadIdx.x >> 6);   // grid = NN/4 exactly
    int lane = threadIdx.x & 63;
    int sub  = lane >> 3;          // edge slot within group of 8
    int dimb = lane & 7;           // 16B chunk within 128B row
    const uint4* T4 = (const uint4*)T2;   // 8 uint4 per dense 128B row
    float dv = dinv[node];
    float sn8 = dv * dv * 0.125f;  // exact /8: 8 identical partials sum back to x*sn
    uint4 sv = T4[(size_t)node * 8 + dimb];
    f32x2 a0, a1, a2, a3;
    a0.x = __uint_as_float(sv.x << 16) * sn8;  a0.y = __uint_as_float(sv.x & 0xFFFF0000u) * sn8;
    a1.x = __uint_as_float(sv.y << 16) * sn8;  a1.y = __uint_as_float(sv.y & 0xFFFF0000u) * sn8;
    a2.x = __uint_as_float(sv.z << 16) * sn8;  a2.y = __uint_as_float(sv.z & 0xFFFF0000u) * sn8;
    a3.x = __uint_as_float(sv.w << 16) * sn8;  a3.y = __uint_as_float(sv.w & 0xFFFF0000u) * sn8;
    int base = row_start[node], end = row_start[node + 1];
    if (end > base) {
        for (int c0 = base; c0 < end; c0 += 64) {
            int idx = c0 + lane;
            int cl = min(idx, end - 1);
            int s = csr[cl];
            float wv = (idx < end) ? dinv[s] * dv : 0.f;   // clamp lanes neutralized
            int ng = min(64, end - c0);
            for (int g = 0; g * 8 < ng; ++g) {
                int   sq = __shfl(s,  g * 8 + sub);
                float wq = __shfl(wv, g * 8 + sub);
                uint4 v = T4[(size_t)sq * 8 + dimb];       // 8 rows per instruction
                f32x2 wv2; wv2.x = wq; wv2.y = wq;
                f32x2 xv;
                xv.x = __uint_as_float(v.x << 16); xv.y = __uint_as_float(v.x & 0xFFFF0000u);
                a0 = __builtin_elementwise_fma(xv, wv2, a0);
                xv.x = __uint_as_float(v.y << 16); xv.y = __uint_as_float(v.y & 0xFFFF0000u);
                a1 = __builtin_elementwise_fma(xv, wv2, a1);
                xv.x = __uint_as_float(v.z << 16); xv.y = __uint_as_float(v.z & 0xFFFF0000u);
                a2 = __builtin_elementwise_fma(xv, wv2, a2);
                xv.x = __uint_as_float(v.w << 16); xv.y = __uint_as_float(v.w & 0xFFFF0000u);
                a3 = __builtin_elementwise_fma(xv, wv2, a3);
            }
        }
    }
    // butterfly reduce the 8 edge-slot partials (lanes xor 8,16,32)
#pragma unroll
    for (int mgap = 8; mgap < 64; mgap <<= 1) {
        a0.x += __shfl_xor(a0.x, mgap); a0.y += __shfl_xor(a0.y, mgap);
        a1.x += __shfl_xor(a1.x, mgap); a1.y += __shfl_xor(a1.y, mgap);
        a2.x += __shfl_xor(a2.x, mgap); a2.y += __shfl_xor(a2.y, mgap);
        a3.x += __shfl_xor(a3.x, mgap); a3.y += __shfl_xor(a3.y, mgap);
    }
    if (lane < 8) {
        float4 ba = ((const float4*)b2)[lane * 2];
        float4 bb = ((const float4*)b2)[lane * 2 + 1];
        float4 o0, o1;
        o0.x = a0.x + ba.x; o0.y = a0.y + ba.y; o0.z = a1.x + ba.z; o0.w = a1.y + ba.w;
        o1.x = a2.x + bb.x; o1.y = a2.y + bb.y; o1.z = a3.x + bb.z; o1.w = a3.y + bb.w;
        ((float4*)outp)[(size_t)node * 16 + lane * 2]     = o0;
        ((float4*)outp)[(size_t)node * 16 + lane * 2 + 1] = o1;
    }
}

extern "C" void kernel_launch(void* const* d_in, const int* in_sizes, int n_in,
                              void* d_out, int out_size, void* d_ws, size_t ws_size,
                              hipStream_t stream) {
    const float* x  = (const float*)d_in[0];
    const int*   ei = (const int*)d_in[1];
    const float* W1 = (const float*)d_in[2];
    const float* b1 = (const float*)d_in[3];
    const float* W2 = (const float*)d_in[4];
    const float* b2 = (const float*)d_in[5];
    float* out = (float*)d_out;
    const int* src = ei;
    const int* dst = ei + NE;

    char* ws = (char*)d_ws;
    unsigned short* xb        = (unsigned short*)(ws + 0);
    unsigned short* H         = (unsigned short*)(ws + 0);         // overlaps dead xb
    char*           P         = ws + 25600000;
    unsigned short* T2        = (unsigned short*)(ws + 25600000);  // overlaps dead P
    int*            ghist     = (int*)(ws + 25600000);             // dead before agg1
    int*            boffT     = (int*)(ws + 27200512);
    int*            tot       = (int*)(ws + 28801024);
    int*            bbase     = (int*)(ws + 28807276);
    int*            row_start = (int*)(ws + 51200000);
    float*          dinv      = (float*)(ws + 51600004);
    int*            csr       = (int*)(ws + 52000004);
    int*            ebuf      = (int*)(ws + 58400004);

    k_pre  <<<NBXB + NBH, 256, 0, stream>>>(x, xb, dst, ghist);
    k_scanB<<<(NBUCK + 31) / 32, 256, 0, stream>>>(ghist, boffT, tot);
    k_place<<<NBH, 256, 0, stream>>>(src, dst, tot, boffT, ebuf, bbase);
    k_binC <<<NBUCK, 256, 0, stream>>>(bbase, tot, ebuf, row_start, dinv, csr);

    k_agg1<<<NN / 4, 256, 0, stream>>>(xb, dinv, row_start, csr, P);
    k_g1  <<<NBGG, 256, 0, stream>>>(P, W1, b1, H);
    k_g2  <<<NBGG, 256, 0, stream>>>(H, W2, T2);
    k_agg2<<<NN / 4, 256, 0, stream>>>(dinv, row_start, csr, T2, b2, out);
}

// Round 12
// 276.297 us; speedup vs baseline: 1.1216x; 1.1216x over previous
//
#include <hip/hip_runtime.h>

#define NN 100000
#define NE 1600000
#define NBUCK 1563     // ceil(NN/64)
#define NBH 256        // histogram/placement chunks
#define CHUNK 6250     // NE/NBH
#define NSEG 8         // k_scanB segments per bucket
#define SEGC (NBH/NSEG) // 32 chunks per segment
#define NBXB 12500     // NN*32/256 blocks for x->bf16
#define NBG 1563       // row tiles for fused GEMM
#define NBGG 782       // k_gemm12 grid (2 tiles/block, balanced)

// ws layout (bytes):
//   xb:    0           (25,600,000)  bf16 x                      [live: k_pre..k_agg1]
//   P:     25,600,000  (25,600,000)  per-node 256B slot          [live: k_agg1..k_agg2]
//     ghist: 25,600,000 (1,600,512)  dead after k_scanB   (overlaps P)
//     boffT: 27,200,512 (1,600,512)  dead after k_place   (overlaps P)
//     tot:   28,801,024 (6,252)      dead after k_binC
//     bbase: 28,807,276 (6,252)      written by k_place blk0; dead after k_binC
//   row_start: 51,200,000 ((NN+1)*4)
//   dinv:  51,600,004  (400,000)
//   csr:   52,000,004  (6,400,000)
//   ebuf:  58,400,004  (6,400,000)   dead after k_binC
//   Wg1:   64,800,004  (32,768)      W1 bf16 fragment-ordered [k_pre..k_gemm12]
//   Wg2:   64,832,772  (16,384)      W2 bf16 fragment-ordered
// total 64.85 MB. No memsets needed.

typedef short bf16x8 __attribute__((ext_vector_type(8)));
typedef float f32x4  __attribute__((ext_vector_type(4)));
typedef float f32x2  __attribute__((ext_vector_type(2)));

__device__ __forceinline__ float b2f(unsigned short u) {
    return __uint_as_float(((unsigned int)u) << 16);
}
__device__ __forceinline__ unsigned short f2b(float f) {
    unsigned int x = __float_as_uint(f);
    x += 0x7FFFu + ((x >> 16) & 1u);   // RNE
    return (unsigned short)(x >> 16);
}

// ---- fused: x->bf16 [0,NBXB) + hist [NBXB,NBXB+NBH) + W1/W2 fragment conversion ----
__global__ __launch_bounds__(256) void k_pre(const float* __restrict__ x,
                                             unsigned short* __restrict__ xb,
                                             const int* __restrict__ dst,
                                             int* __restrict__ ghist,
                                             const float* __restrict__ W1,
                                             const float* __restrict__ W2,
                                             unsigned short* __restrict__ Wg1,
                                             unsigned short* __restrict__ Wg2) {
    int b = blockIdx.x;
    if (b < NBXB) {
        int id = b * 256 + threadIdx.x;
        float4 v = ((const float4*)x)[id];
        ushort4 o;
        o.x = f2b(v.x); o.y = f2b(v.y); o.z = f2b(v.z); o.w = f2b(v.w);
        ((ushort4*)xb)[id] = o;
        return;
    }
    if (b == NBXB + NBH) {            // W1 -> fragment-ordered bf16 (16384 elems)
        for (int i = threadIdx.x; i < 16384; i += 256) {
            int j = i & 7, l = (i >> 3) & 63, ks = (i >> 9) & 3, ct = i >> 11;
            int k = ks * 32 + ((l >> 4) << 3) + j;
            int c = ct * 16 + (l & 15);
            Wg1[i] = f2b(W1[k * 128 + c]);
        }
        return;
    }
    if (b == NBXB + NBH + 1) {        // W2 -> fragment-ordered bf16 (8192 elems)
        for (int i = threadIdx.x; i < 8192; i += 256) {
            int j = i & 7, l = (i >> 3) & 63, ks = (i >> 9) & 3, ct = i >> 11;
            int k = ks * 32 + ((l >> 4) << 3) + j;
            int c = ct * 16 + (l & 15);
            Wg2[i] = f2b(W2[k * 64 + c]);
        }
        return;
    }
    __shared__ int h[NBUCK];
    int tid = threadIdx.x;
    int i = b - NBXB;
    for (int k = tid; k < NBUCK; k += 256) h[k] = 0;
    __syncthreads();
    int e0 = i * CHUNK;
    for (int e = e0 + tid; e < e0 + CHUNK; e += 256) {
        unsigned d = (unsigned)dst[e];
        if (d < NN) atomicAdd(&h[d >> 6], 1);
    }
    __syncthreads();
    for (int k = tid; k < NBUCK; k += 256) ghist[i * NBUCK + k] = h[k];
}

// ---- per-bucket scan over chunks, 8-way segmented: boffT[i][k], tot[k] ----
__global__ __launch_bounds__(256) void k_scanB(const int* __restrict__ ghist,
                                               int* __restrict__ boffT,
                                               int* __restrict__ tot) {
    __shared__ int part[NSEG][32];
    int kk = threadIdx.x & 31, seg = threadIdx.x >> 5;
    int k = blockIdx.x * 32 + kk;
    bool ok = (k < NBUCK);
    int i0 = seg * SEGC;
    int S = 0;
    if (ok) {
#pragma unroll 8
        for (int i = i0; i < i0 + SEGC; ++i) S += ghist[i * NBUCK + k];
    }
    part[seg][kk] = S;
    __syncthreads();
    int pre = 0;
#pragma unroll
    for (int s2 = 0; s2 < NSEG; ++s2) pre += (s2 < seg) ? part[s2][kk] : 0;
    if (ok) {
        int run = pre;
#pragma unroll 8
        for (int i = i0; i < i0 + SEGC; ++i) {
            int c = ghist[i * NBUCK + k];
            boffT[i * NBUCK + k] = run;      // coalesced in k
            run += c;
        }
        if (seg == NSEG - 1) tot[k] = run;
    }
}

// ---- placement: computes bbase locally (scanT folded in), XCD-swizzled chunks ----
__global__ __launch_bounds__(256) void k_place(const int* __restrict__ src,
                                               const int* __restrict__ dst,
                                               const int* __restrict__ tot,
                                               const int* __restrict__ boffT,
                                               int* __restrict__ ebuf,
                                               int* __restrict__ bbase_out) {
    __shared__ int cur[NBUCK];
    __shared__ int s[256];
    const int tid = threadIdx.x, bid = blockIdx.x;
    const int i = ((bid & 7) * (NBH / 8)) + (bid >> 3);   // consecutive chunks same XCD
    int k0 = tid * 7;
    int v[7]; int S = 0;
#pragma unroll
    for (int q = 0; q < 7; ++q) {
        int k = k0 + q;
        v[q] = (k < NBUCK) ? tot[k] : 0;
        S += v[q];
    }
    s[tid] = S;
    __syncthreads();
    for (int off = 1; off < 256; off <<= 1) {
        int t = (tid >= off) ? s[tid - off] : 0;
        __syncthreads();
        s[tid] += t;
        __syncthreads();
    }
    int run = s[tid] - S;   // exclusive
#pragma unroll
    for (int q = 0; q < 7; ++q) {
        int k = k0 + q;
        if (k < NBUCK) {
            cur[k] = run + boffT[i * NBUCK + k];
            if (bid == 0) bbase_out[k] = run;    // publish for k_binC
            run += v[q];
        }
    }
    __syncthreads();
    int e0 = i * CHUNK;
    for (int e = e0 + tid; e < e0 + CHUNK; e += 256) {
        unsigned d = (unsigned)dst[e];
        if (d >= NN) continue;
        unsigned sv = (unsigned)src[e];
        if (sv >= NN) sv = 0;
        int pos = atomicAdd(&cur[d >> 6], 1);
        ebuf[pos] = (int)(sv | ((d & 63u) << 17));
    }
}

// ---- per-bucket: count per node, write row_start/dinv, place src-only csr ----
__global__ __launch_bounds__(256) void k_binC(const int* __restrict__ bbase,
                                              const int* __restrict__ tot,
                                              const int* __restrict__ ebuf,
                                              int* __restrict__ row_start,
                                              float* __restrict__ dinv,
                                              int* __restrict__ csr) {
    __shared__ int cnt[64], excl[64], cur[64];
    int b = blockIdx.x, tid = threadIdx.x;
    int n0 = b * 64;
    int base = bbase[b], end = base + tot[b];
    if (tid < 64) cnt[tid] = 0;
    __syncthreads();
    for (int i = base + tid; i < end; i += 256)
        atomicAdd(&cnt[((unsigned)ebuf[i]) >> 17], 1);
    __syncthreads();
    if (tid == 0) {
        int run = 0;
        for (int t = 0; t < 64; ++t) { excl[t] = run; run += cnt[t]; }
    }
    __syncthreads();
    if (tid < 64) {
        int node = n0 + tid;
        if (node < NN) {
            row_start[node] = base + excl[tid];
            dinv[node] = rsqrtf((float)cnt[tid] + 1.0f);
        }
        cur[tid] = base + excl[tid];
    }
    if (b == NBUCK - 1 && tid == 0) row_start[NN] = end;
    __syncthreads();
    for (int i = base + tid; i < end; i += 256) {
        unsigned rec = (unsigned)ebuf[i];
        int pos = atomicAdd(&cur[rec >> 17], 1);
        csr[pos] = (int)(rec & 0x1FFFFu);
    }
}

// ---- layer-1 aggregate: 4 neighbor rows PER GATHER INSTRUCTION (at service roofline) ----
__global__ __launch_bounds__(256) void k_agg1(const unsigned short* __restrict__ xb,
                                              const float* __restrict__ dinv,
                                              const int* __restrict__ row_start,
                                              const int* __restrict__ csr,
                                              char* __restrict__ P) {
    int node = blockIdx.x * 4 + (threadIdx.x >> 6);   // grid = NN/4 exactly
    int lane = threadIdx.x & 63;
    int sub  = lane >> 4;          // edge slot within group of 4
    int dimb = lane & 15;          // 16B chunk within 256B row
    const uint4* X4 = (const uint4*)xb;   // 16 uint4 per 256B row
    float dv = dinv[node];
    float sn4 = dv * dv * 0.25f;   // exact /4: 4 identical partials sum back to x*sn
    uint4 sv = X4[(size_t)node * 16 + dimb];
    f32x2 a0, a1, a2, a3;
    a0.x = __uint_as_float(sv.x << 16) * sn4;  a0.y = __uint_as_float(sv.x & 0xFFFF0000u) * sn4;
    a1.x = __uint_as_float(sv.y << 16) * sn4;  a1.y = __uint_as_float(sv.y & 0xFFFF0000u) * sn4;
    a2.x = __uint_as_float(sv.z << 16) * sn4;  a2.y = __uint_as_float(sv.z & 0xFFFF0000u) * sn4;
    a3.x = __uint_as_float(sv.w << 16) * sn4;  a3.y = __uint_as_float(sv.w & 0xFFFF0000u) * sn4;
    int base = row_start[node], end = row_start[node + 1];
    for (int c0 = base; c0 < end; c0 += 64) {
        int idx = c0 + lane;
        int cl = min(idx, end - 1);
        int s = csr[cl];
        float wv = (idx < end) ? dinv[s] * dv : 0.f;   // clamp lanes neutralized
        int ng = min(64, end - c0);
        for (int g = 0; g * 4 < ng; ++g) {
            int   sq = __shfl(s,  g * 4 + sub);
            float wq = __shfl(wv, g * 4 + sub);
            uint4 v = X4[(size_t)sq * 16 + dimb];      // 4 rows per instruction
            f32x2 wv2; wv2.x = wq; wv2.y = wq;
            f32x2 xv;
            xv.x = __uint_as_float(v.x << 16); xv.y = __uint_as_float(v.x & 0xFFFF0000u);
            a0 = __builtin_elementwise_fma(xv, wv2, a0);
            xv.x = __uint_as_float(v.y << 16); xv.y = __uint_as_float(v.y & 0xFFFF0000u);
            a1 = __builtin_elementwise_fma(xv, wv2, a1);
            xv.x = __uint_as_float(v.z << 16); xv.y = __uint_as_float(v.z & 0xFFFF0000u);
            a2 = __builtin_elementwise_fma(xv, wv2, a2);
            xv.x = __uint_as_float(v.w << 16); xv.y = __uint_as_float(v.w & 0xFFFF0000u);
            a3 = __builtin_elementwise_fma(xv, wv2, a3);
        }
    }
    // butterfly reduce the 4 edge-slot partials (lanes xor 16, 32)
#pragma unroll
    for (int mgap = 16; mgap < 64; mgap <<= 1) {
        a0.x += __shfl_xor(a0.x, mgap); a0.y += __shfl_xor(a0.y, mgap);
        a1.x += __shfl_xor(a1.x, mgap); a1.y += __shfl_xor(a1.y, mgap);
        a2.x += __shfl_xor(a2.x, mgap); a2.y += __shfl_xor(a2.y, mgap);
        a3.x += __shfl_xor(a3.x, mgap); a3.y += __shfl_xor(a3.y, mgap);
    }
    if (lane < 16) {
        uint4 o;
        o.x = (unsigned)f2b(a0.x) | ((unsigned)f2b(a0.y) << 16);
        o.y = (unsigned)f2b(a1.x) | ((unsigned)f2b(a1.y) << 16);
        o.z = (unsigned)f2b(a2.x) | ((unsigned)f2b(a2.y) << 16);
        o.w = (unsigned)f2b(a3.x) | ((unsigned)f2b(a3.y) << 16);
        ((uint4*)(P + (size_t)node * 256))[lane] = o;
    }
}

// ---- fused GEMM1+GEMM2 (MFMA): weights read as fragment-ordered bf16 from GLOBAL
//      (L2-resident 48KB, pre-converted by k_pre) -> LDS = Cl only (17.4KB) ->
//      occupancy VGPR-capped (~4-5 blocks/CU) instead of LDS-capped at 2.
//      Cl padded to 136 shorts/row (bank-conflict-free); 2 barriers/tile
//      (cross-lane LDS exchange REQUIRES barriers - round-7 lesson).
//      GEMM2 output: direct accumulator->P stores (round-8 proven).
__global__ __launch_bounds__(256) void k_gemm12(const unsigned short* __restrict__ Wg1,
                                                const float* __restrict__ b1,
                                                const unsigned short* __restrict__ Wg2,
                                                char* __restrict__ P) {
    __shared__ __align__(16) short Cl[4][16][136];  // per-wave transpose buffer
    const int tid = threadIdx.x;
    const int w = tid >> 6, lane = tid & 63;
    const int quad = lane >> 4, l15 = lane & 15;

    float bias1[8];
#pragma unroll
    for (int ct = 0; ct < 8; ++ct) bias1[ct] = b1[ct * 16 + l15];

    for (int t = blockIdx.x; t < NBG; t += NBGG) {
        const int r0 = t * 64;
        const int m = r0 + w * 16 + l15;
        const bool mok = (m < NN);
        bf16x8 a[4];
#pragma unroll
        for (int ks = 0; ks < 4; ++ks) {
            if (mok) a[ks] = *(const bf16x8*)(P + (size_t)m * 256 + (ks * 32 + quad * 8) * 2);
            else     a[ks] = bf16x8{0,0,0,0,0,0,0,0};
        }
#pragma unroll
        for (int ct = 0; ct < 8; ++ct) {
            f32x4 c = {0.f, 0.f, 0.f, 0.f};
#pragma unroll
            for (int ks = 0; ks < 4; ++ks) {
                bf16x8 b = *(const bf16x8*)&Wg1[((ct * 4 + ks) * 64 + lane) * 8];
                c = __builtin_amdgcn_mfma_f32_16x16x32_bf16(a[ks], b, c, 0, 0, 0);
            }
#pragma unroll
            for (int r = 0; r < 4; ++r)
                Cl[w][quad * 4 + r][ct * 16 + l15] =
                    (short)f2b(fmaxf(c[r] + bias1[ct], 0.f));
        }
        __syncthreads();   // B1: Cl writes -> cross-lane a2 reads
        bf16x8 a2[4];
#pragma unroll
        for (int ks = 0; ks < 4; ++ks)
            a2[ks] = *(const bf16x8*)&Cl[w][l15][ks * 32 + quad * 8];
#pragma unroll
        for (int ct = 0; ct < 4; ++ct) {
            f32x4 c = {0.f, 0.f, 0.f, 0.f};
#pragma unroll
            for (int ks = 0; ks < 4; ++ks) {
                bf16x8 b = *(const bf16x8*)&Wg2[((ct * 4 + ks) * 64 + lane) * 8];
                c = __builtin_amdgcn_mfma_f32_16x16x32_bf16(a2[ks], b, c, 0, 0, 0);
            }
            // direct store: quad's 16 lanes write 32 contiguous bytes of node's row
#pragma unroll
            for (int r = 0; r < 4; ++r) {
                int node = r0 + w * 16 + quad * 4 + r;
                if (node < NN)
                    *(unsigned short*)(P + (size_t)node * 256 + (ct * 16 + l15) * 2) =
                        f2b(c[r]);
            }
        }
        __syncthreads();   // B2: this-tile a2 reads -> next-tile Cl writes
    }
}

// ---- layer-2 aggregate + epilogue: 8 neighbor rows PER GATHER INSTRUCTION ----
__global__ __launch_bounds__(256) void k_agg2(const float* __restrict__ dinv,
                                              const int* __restrict__ row_start,
                                              const int* __restrict__ csr,
                                              const char* __restrict__ P,
                                              const float* __restrict__ b2,
                                              float* __restrict__ outp) {
    int node = blockIdx.x * 4 + (threadIdx.x >> 6);   // grid = NN/4 exactly
    int lane = threadIdx.x & 63;
    int sub  = lane >> 3;          // edge slot within group of 8
    int dimb = lane & 7;           // 16B chunk within 128B row
    const uint4* P4 = (const uint4*)P;   // 16 uint4 per 256B slot; first 8 live
    float dv = dinv[node];
    float sn8 = dv * dv * 0.125f;  // exact /8: 8 identical partials sum back to x*sn
    uint4 sv = P4[(size_t)node * 16 + dimb];
    f32x2 a0, a1, a2, a3;
    a0.x = __uint_as_float(sv.x << 16) * sn8;  a0.y = __uint_as_float(sv.x & 0xFFFF0000u) * sn8;
    a1.x = __uint_as_float(sv.y << 16) * sn8;  a1.y = __uint_as_float(sv.y & 0xFFFF0000u) * sn8;
    a2.x = __uint_as_float(sv.z << 16) * sn8;  a2.y = __uint_as_float(sv.z & 0xFFFF0000u) * sn8;
    a3.x = __uint_as_float(sv.w << 16) * sn8;  a3.y = __uint_as_float(sv.w & 0xFFFF0000u) * sn8;
    int base = row_start[node], end = row_start[node + 1];
    if (end > base) {
        for (int c0 = base; c0 < end; c0 += 64) {
            int idx = c0 + lane;
            int cl = min(idx, end - 1);
            int s = csr[cl];
            float wv = (idx < end) ? dinv[s] * dv : 0.f;   // clamp lanes neutralized
            int ng = min(64, end - c0);
            for (int g = 0; g * 8 < ng; ++g) {
                int   sq = __shfl(s,  g * 8 + sub);
                float wq = __shfl(wv, g * 8 + sub);
                uint4 v = P4[(size_t)sq * 16 + dimb];      // 8 rows per instruction
                f32x2 wv2; wv2.x = wq; wv2.y = wq;
                f32x2 xv;
                xv.x = __uint_as_float(v.x << 16); xv.y = __uint_as_float(v.x & 0xFFFF0000u);
                a0 = __builtin_elementwise_fma(xv, wv2, a0);
                xv.x = __uint_as_float(v.y << 16); xv.y = __uint_as_float(v.y & 0xFFFF0000u);
                a1 = __builtin_elementwise_fma(xv, wv2, a1);
                xv.x = __uint_as_float(v.z << 16); xv.y = __uint_as_float(v.z & 0xFFFF0000u);
                a2 = __builtin_elementwise_fma(xv, wv2, a2);
                xv.x = __uint_as_float(v.w << 16); xv.y = __uint_as_float(v.w & 0xFFFF0000u);
                a3 = __builtin_elementwise_fma(xv, wv2, a3);
            }
        }
    }
    // butterfly reduce the 8 edge-slot partials (lanes xor 8,16,32)
#pragma unroll
    for (int mgap = 8; mgap < 64; mgap <<= 1) {
        a0.x += __shfl_xor(a0.x, mgap); a0.y += __shfl_xor(a0.y, mgap);
        a1.x += __shfl_xor(a1.x, mgap); a1.y += __shfl_xor(a1.y, mgap);
        a2.x += __shfl_xor(a2.x, mgap); a2.y += __shfl_xor(a2.y, mgap);
        a3.x += __shfl_xor(a3.x, mgap); a3.y += __shfl_xor(a3.y, mgap);
    }
    if (lane < 8) {
        float4 ba = ((const float4*)b2)[lane * 2];
        float4 bb = ((const float4*)b2)[lane * 2 + 1];
        float4 o0, o1;
        o0.x = a0.x + ba.x; o0.y = a0.y + ba.y; o0.z = a1.x + ba.z; o0.w = a1.y + ba.w;
        o1.x = a2.x + bb.x; o1.y = a2.y + bb.y; o1.z = a3.x + bb.z; o1.w = a3.y + bb.w;
        ((float4*)outp)[(size_t)node * 16 + lane * 2]     = o0;
        ((float4*)outp)[(size_t)node * 16 + lane * 2 + 1] = o1;
    }
}

extern "C" void kernel_launch(void* const* d_in, const int* in_sizes, int n_in,
                              void* d_out, int out_size, void* d_ws, size_t ws_size,
                              hipStream_t stream) {
    const float* x  = (const float*)d_in[0];
    const int*   ei = (const int*)d_in[1];
    const float* W1 = (const float*)d_in[2];
    const float* b1 = (const float*)d_in[3];
    const float* W2 = (const float*)d_in[4];
    const float* b2 = (const float*)d_in[5];
    float* out = (float*)d_out;
    const int* src = ei;
    const int* dst = ei + NE;

    char* ws = (char*)d_ws;
    unsigned short* xb        = (unsigned short*)(ws + 0);
    char*           P         = ws + 25600000;
    int*            ghist     = (int*)(ws + 25600000);   // overlaps P (dead first)
    int*            boffT     = (int*)(ws + 27200512);
    int*            tot       = (int*)(ws + 28801024);
    int*            bbase     = (int*)(ws + 28807276);
    int*            row_start = (int*)(ws + 51200000);
    float*          dinv      = (float*)(ws + 51600004);
    int*            csr       = (int*)(ws + 52000004);
    int*            ebuf      = (int*)(ws + 58400004);
    unsigned short* Wg1       = (unsigned short*)(ws + 64800004);
    unsigned short* Wg2       = (unsigned short*)(ws + 64832772);

    k_pre  <<<NBXB + NBH + 2, 256, 0, stream>>>(x, xb, dst, ghist, W1, W2, Wg1, Wg2);
    k_scanB<<<(NBUCK + 31) / 32, 256, 0, stream>>>(ghist, boffT, tot);
    k_place<<<NBH, 256, 0, stream>>>(src, dst, tot, boffT, ebuf, bbase);
    k_binC <<<NBUCK, 256, 0, stream>>>(bbase, tot, ebuf, row_start, dinv, csr);

    k_agg1  <<<NN / 4, 256, 0, stream>>>(xb, dinv, row_start, csr, P);
    k_gemm12<<<NBGG, 256, 0, stream>>>(Wg1, b1, Wg2, P);
    k_agg2  <<<NN / 4, 256, 0, stream>>>(dinv, row_start, csr, P, b2, out);
}